// Round 1
// baseline (241.825 us; speedup 1.0000x reference)
//
#include <hip/hip_runtime.h>

#define BB   4
#define CC   256
#define HH   128
#define WW   128
#define PADW 4
#define KOUT 81

#define TH   8        // output rows per block (one per wave)
#define SW   16       // output cols per block (one MFMA M-tile)
#define KC   32       // channels per chunk (one MFMA K)
#define NCHUNK (CC / KC)
#define AK   40       // padded K-stride in LDS elements (80B: 16B-aligned b128, 2-way banks)

typedef _Float16 half8  __attribute__((ext_vector_type(8)));
typedef float    f32x4  __attribute__((ext_vector_type(4)));

__global__ __launch_bounds__(512)
void corr_mfma_kernel(const float* __restrict__ i1,
                      const float* __restrict__ i2,
                      float* __restrict__ out)
{
    // A: [8 rows][16 m][AK]  B: [16 rows][32 q][AK]
    __shared__ _Float16 Ald[TH * 16 * AK];      // 10240 B
    __shared__ _Float16 Bld[16 * 32 * AK];      // 40960 B

    const int t    = threadIdx.x;
    const int wave = t >> 6;          // 0..7  -> output row within tile
    const int lane = t & 63;
    const int l15  = lane & 15;
    const int quad = lane >> 4;

    const int b  = blockIdx.z;
    const int h0 = blockIdx.y * TH;
    const int w0 = blockIdx.x * SW;

    f32x4 acc[9][2];
#pragma unroll
    for (int dy = 0; dy < 9; ++dy)
#pragma unroll
        for (int tt = 0; tt < 2; ++tt)
            acc[dy][tt] = (f32x4){0.f, 0.f, 0.f, 0.f};

    // A staging decomposition: 512 = 16 m * 16 kpair * 2 rowgroup
    const int am  = t & 15;
    const int aj  = (t >> 4) & 15;    // k-pair index
    const int arg = t >> 8;           // row group (0..1), 4 rows each
    // B staging decomposition: 512 = 32 q * 16 kpair  (q >= 24 idle)
    const int bq  = t & 31;
    const int bj  = t >> 5;

    const size_t strideC = (size_t)HH * WW;
    const float* i1b = i1 + (size_t)b * CC * strideC;
    const float* i2b = i2 + (size_t)b * CC * strideC;

    for (int ch = 0; ch < NCHUNK; ++ch) {
        const int c0 = ch * KC;

        // ---- stage A (i1 tile): always in-bounds ----
        {
            const float* p0 = i1b + (size_t)(c0 + 2 * aj) * strideC
                                  + (size_t)(h0 + arg * 4) * WW + (w0 + am);
#pragma unroll
            for (int rr = 0; rr < 4; ++rr) {
                float v0 = p0[(size_t)rr * WW];
                float v1 = p0[(size_t)rr * WW + strideC];
                const int row = arg * 4 + rr;
                _Float16* d = &Ald[(row * 16 + am) * AK + 2 * aj];
                d[0] = (_Float16)v0;
                d[1] = (_Float16)v1;
            }
        }
        // ---- stage B (i2 padded neighborhood): zero-fill OOB ----
        if (bq < 24) {
            const int col   = w0 - PADW + bq;
            const bool cok  = (col >= 0) && (col < WW);
            const float* p0 = i2b + (size_t)(c0 + 2 * bj) * strideC + col;
#pragma unroll
            for (int r = 0; r < 16; ++r) {
                const int row = h0 - PADW + r;
                const bool ok = cok && (row >= 0) && (row < HH);
                float v0 = ok ? p0[(size_t)row * WW] : 0.f;
                float v1 = ok ? p0[(size_t)row * WW + strideC] : 0.f;
                _Float16* d = &Bld[(r * 32 + bq) * AK + 2 * bj];
                d[0] = (_Float16)v0;
                d[1] = (_Float16)v1;
            }
        }
        __syncthreads();

        // ---- compute: one output row per wave, all 9 dy ----
        {
            const half8 a = *(const half8*)&Ald[(wave * 16 + l15) * AK + quad * 8];
#pragma unroll
            for (int dy = 0; dy < 9; ++dy) {
                const int r = wave + dy;   // i2 LDS row for this dy
                const half8 b0 = *(const half8*)&Bld[(r * 32 + l15) * AK + quad * 8];
                acc[dy][0] = __builtin_amdgcn_mfma_f32_16x16x32_f16(a, b0, acc[dy][0], 0, 0, 0);
                const half8 b1 = *(const half8*)&Bld[(r * 32 + 16 + l15) * AK + quad * 8];
                acc[dy][1] = __builtin_amdgcn_mfma_f32_16x16x32_f16(a, b1, acc[dy][1], 0, 0, 0);
            }
        }
        __syncthreads();
    }

    // ---- epilogue: D[p][q], p = quad*4+reg, q = l15 + 16*tile, dx = q - p ----
    const int h = h0 + wave;
#pragma unroll
    for (int dy = 0; dy < 9; ++dy) {
#pragma unroll
        for (int tt = 0; tt < 2; ++tt) {
#pragma unroll
            for (int reg = 0; reg < 4; ++reg) {
                const int p  = quad * 4 + reg;
                const int q  = l15 + 16 * tt;
                const int dx = q - p;
                if (dx >= 0 && dx <= 8) {
                    out[(((size_t)b * KOUT + (dy * 9 + dx)) * HH + h) * WW + (w0 + p)] =
                        acc[dy][tt][reg];
                }
            }
        }
    }
}

extern "C" void kernel_launch(void* const* d_in, const int* in_sizes, int n_in,
                              void* d_out, int out_size, void* d_ws, size_t ws_size,
                              hipStream_t stream)
{
    (void)in_sizes; (void)n_in; (void)d_ws; (void)ws_size; (void)out_size;
    const float* i1 = (const float*)d_in[0];
    const float* i2 = (const float*)d_in[1];
    float* out = (float*)d_out;

    dim3 grid(WW / SW, HH / TH, BB);   // (8, 16, 4) = 512 blocks
    dim3 block(512);
    corr_mfma_kernel<<<grid, block, 0, stream>>>(i1, i2, out);
}

// Round 2
// 186.188 us; speedup vs baseline: 1.2988x; 1.2988x over previous
//
#include <hip/hip_runtime.h>

#define BB   4
#define CC   256
#define HH   128
#define WW   128
#define PAD  4
#define KOUT 81

#define TH   8        // output rows per block (one per wave)
#define SW   16       // output cols per block (one MFMA M-tile)
#define KC   32       // channels per chunk (one MFMA K)
#define NCHUNK (CC / KC)
#define AK   40       // padded K-stride per LDS point (80 B: 16B-aligned, stride-20-words => conflict-free)

typedef _Float16 half8 __attribute__((ext_vector_type(8)));
typedef float    f32x4 __attribute__((ext_vector_type(4)));

__global__ __launch_bounds__(512, 4)
void corr_mfma2(const float* __restrict__ i1,
                const float* __restrict__ i2,
                float* __restrict__ out)
{
    // A: 128 pts (8 rows x 16 m), B: 512 pts (16 rows x 32 q; q<24 valid,
    // q>=24 garbage -> only feeds dx>8 outputs which are never stored)
    __shared__ _Float16 Ald[128 * AK];   // 10240 B
    __shared__ _Float16 Bld[512 * AK];   // 40960 B

    const int t    = threadIdx.x;
    const int wave = t >> 6;
    const int lane = t & 63;
    const int l15  = lane & 15;
    const int quad = lane >> 4;

    const int b  = blockIdx.z;
    const int h0 = blockIdx.y * TH;
    const int w0 = blockIdx.x * SW;

    const size_t strideC = (size_t)HH * WW;
    const float* i1b = i1 + (size_t)b * CC * strideC;
    const float* i2b = i2 + (size_t)b * CC * strideC;

    // ---- staging role: waves 0..5 stage B (384 threads, one (r,q) point each),
    //      waves 6..7 stage A (128 threads, one (r,m) point each). Each thread
    //      owns ALL 32 channels of its point -> contiguous K-run in LDS.
    bool valid;
    const float* gptr;
    _Float16* ldst;
    if (t < 384) {
        const int sq  = t % 24;          // 0..23
        const int sr  = t / 24;          // 0..15
        const int col = w0 - PAD + sq;
        const int row = h0 - PAD + sr;
        valid = (col >= 0) && (col < WW) && (row >= 0) && (row < HH);
        const int crow = valid ? row : 0;
        const int ccol = valid ? col : 0;
        gptr = i2b + (size_t)crow * WW + ccol;
        ldst = &Bld[(sr * 32 + sq) * AK];
    } else {
        const int i  = t - 384;
        const int sm = i & 15;           // 0..15
        const int sr = i >> 4;           // 0..7
        valid = true;
        gptr = i1b + (size_t)(h0 + sr) * WW + (w0 + sm);
        ldst = &Ald[(sr * 16 + sm) * AK];
    }

    f32x4 acc[9][2];
#pragma unroll
    for (int dy = 0; dy < 9; ++dy) {
        acc[dy][0] = (f32x4){0.f, 0.f, 0.f, 0.f};
        acc[dy][1] = (f32x4){0.f, 0.f, 0.f, 0.f};
    }

    float v[KC];

    // ---- prologue: stage chunk 0 ----
#pragma unroll
    for (int j = 0; j < KC; ++j)
        v[j] = valid ? gptr[(size_t)j * strideC] : 0.f;
#pragma unroll
    for (int u = 0; u < 4; ++u) {
        half8 hv;
#pragma unroll
        for (int k = 0; k < 8; ++k) hv[k] = (_Float16)v[8 * u + k];
        *(half8*)&ldst[8 * u] = hv;
    }
    __syncthreads();

#pragma unroll 1
    for (int ch = 0; ch < NCHUNK; ++ch) {
        // ---- prefetch next chunk's globals into registers (no wait) ----
        if (ch + 1 < NCHUNK) {
            const float* g = gptr + (size_t)(ch + 1) * KC * strideC;
#pragma unroll
            for (int j = 0; j < KC; ++j)
                v[j] = valid ? g[(size_t)j * strideC] : 0.f;
        }

        // ---- compute current chunk: one output row per wave, 9 dy x 2 N-tiles ----
        {
            const half8 a = *(const half8*)&Ald[(wave * 16 + l15) * AK + quad * 8];
#pragma unroll
            for (int dy = 0; dy < 9; ++dy) {
                const int r = wave + dy;
                const half8 b0 = *(const half8*)&Bld[(r * 32 + l15) * AK + quad * 8];
                acc[dy][0] = __builtin_amdgcn_mfma_f32_16x16x32_f16(a, b0, acc[dy][0], 0, 0, 0);
                const half8 b1 = *(const half8*)&Bld[(r * 32 + 16 + l15) * AK + quad * 8];
                acc[dy][1] = __builtin_amdgcn_mfma_f32_16x16x32_f16(a, b1, acc[dy][1], 0, 0, 0);
            }
        }

        if (ch + 1 < NCHUNK) {
            __syncthreads();   // all waves done reading LDS for chunk ch
#pragma unroll
            for (int u = 0; u < 4; ++u) {
                half8 hv;
#pragma unroll
                for (int k = 0; k < 8; ++k) hv[k] = (_Float16)v[8 * u + k];
                *(half8*)&ldst[8 * u] = hv;
            }
            __syncthreads();   // chunk ch+1 visible
        }
    }

    // ---- epilogue: D[p][q], p = quad*4+reg, q = l15 + 16*tt, dx = q - p ----
    const int h = h0 + wave;
#pragma unroll
    for (int dy = 0; dy < 9; ++dy) {
#pragma unroll
        for (int tt = 0; tt < 2; ++tt) {
#pragma unroll
            for (int reg = 0; reg < 4; ++reg) {
                const int p  = quad * 4 + reg;
                const int dx = l15 + 16 * tt - p;
                if (dx >= 0 && dx <= 8) {
                    out[(((size_t)b * KOUT + (dy * 9 + dx)) * HH + h) * WW + (w0 + p)] =
                        acc[dy][tt][reg];
                }
            }
        }
    }
}

extern "C" void kernel_launch(void* const* d_in, const int* in_sizes, int n_in,
                              void* d_out, int out_size, void* d_ws, size_t ws_size,
                              hipStream_t stream)
{
    (void)in_sizes; (void)n_in; (void)d_ws; (void)ws_size; (void)out_size;
    const float* i1 = (const float*)d_in[0];
    const float* i2 = (const float*)d_in[1];
    float* out = (float*)d_out;

    dim3 grid(WW / SW, HH / TH, BB);   // (8, 16, 4) = 512 blocks, 2 per CU
    dim3 block(512);
    corr_mfma2<<<grid, block, 0, stream>>>(i1, i2, out);
}